// Round 1
// baseline (193.754 us; speedup 1.0000x reference)
//
#include <hip/hip_runtime.h>
#include <cstdint>
#include <math.h>

// SoftmaxGaussian: out_mean/out_var over 10000 MC softmax samples with
// JAX threefry2x32-exact random draw (key(42), shape (512,16,10000)).
//
// Layout facts:
//   N = 512*16*10000 = 81,920,000 ; half = 40,960,000 = 256*16*10000
//   flat j=(b*16+k)*10000+s ; threefry block i in [0,half):
//     counters (i, i+half), key (0,42) -> (z[j=i], z[j=i+half])
//   => block for (b<256,k,s) also yields (b+256,k,s). One kernel block per b.

#define NSAMP 10000
#define HALF_N 40960000u
#define THREADS 512

__device__ __forceinline__ uint32_t rotl32(uint32_t x, int r) {
    return (x << r) | (x >> (32 - r));
}

// JAX threefry2x32, key = (0, 42)
__device__ __forceinline__ void threefry2x32_k42(uint32_t x0, uint32_t x1,
                                                 uint32_t& o0, uint32_t& o1) {
    const uint32_t ks0 = 0u;
    const uint32_t ks1 = 42u;
    const uint32_t ks2 = 0x1BD11BDAu ^ 0u ^ 42u;
    x0 += ks0;
    x1 += ks1;
#define TF_R(r) { x0 += x1; x1 = rotl32(x1, r); x1 ^= x0; }
    TF_R(13) TF_R(15) TF_R(26) TF_R(6)   x0 += ks1; x1 += ks2 + 1u;
    TF_R(17) TF_R(29) TF_R(16) TF_R(24)  x0 += ks2; x1 += ks0 + 2u;
    TF_R(13) TF_R(15) TF_R(26) TF_R(6)   x0 += ks0; x1 += ks1 + 3u;
    TF_R(17) TF_R(29) TF_R(16) TF_R(24)  x0 += ks1; x1 += ks2 + 4u;
    TF_R(13) TF_R(15) TF_R(26) TF_R(6)   x0 += ks2; x1 += ks0 + 5u;
#undef TF_R
    o0 = x0;
    o1 = x1;
}

// JAX uniform(lo=nextafter(-1,0), hi=1) from raw bits (float32 path)
__device__ __forceinline__ float u_from_bits(uint32_t bits) {
    float f = __uint_as_float((bits >> 9) | 0x3F800000u) - 1.0f; // [0,1)
    const float lo = -0.99999994f;                               // nextafterf(-1,0)
    return fmaxf(lo, fmaf(f, 1.0f - lo, lo));
}

__device__ __forceinline__ float wave_sum(float v) {
    v += __shfl_down(v, 32);
    v += __shfl_down(v, 16);
    v += __shfl_down(v, 8);
    v += __shfl_down(v, 4);
    v += __shfl_down(v, 2);
    v += __shfl_down(v, 1);
    return v;
}

__global__ __launch_bounds__(THREADS, 2)
void sg_kernel(const float* __restrict__ mean, const float* __restrict__ var,
               float* __restrict__ out) {
    __shared__ float s_mean[32];  // [h*16+k], h=0 -> batch b, h=1 -> batch b+256
    __shared__ float s_sv[32];    // sqrt(2)*sqrt(var)  (folds the z scale)
    __shared__ float s_red[8 * 64];

    const int tid = threadIdx.x;
    const int b = blockIdx.x;  // 0..255

    if (tid < 32) {
        int h = tid >> 4, k = tid & 15;
        int bg = b + 256 * h;
        s_mean[tid] = mean[bg * 16 + k];
        s_sv[tid] = 1.41421356237309515f * sqrtf(var[bg * 16 + k]);
    }
    __syncthreads();

    float accs0[16], accq0[16], accs1[16], accq1[16];
#pragma unroll
    for (int k = 0; k < 16; k++) { accs0[k] = 0.f; accq0[k] = 0.f; accs1[k] = 0.f; accq1[k] = 0.f; }

    const uint32_t base_bk = (uint32_t)(b * 16) * 10000u;

    for (int s = tid; s < NSAMP; s += THREADS) {
        float x0v[16], x1v[16];
#pragma unroll
        for (int k = 0; k < 16; k++) {
            uint32_t i = base_bk + (uint32_t)(k * 10000) + (uint32_t)s;
            uint32_t o0, o1;
            threefry2x32_k42(i, i + HALF_N, o0, o1);
            float z0 = erfinvf(u_from_bits(o0));
            float z1 = erfinvf(u_from_bits(o1));
            x0v[k] = fmaf(z0, s_sv[k],      s_mean[k]);       // batch b sample
            x1v[k] = fmaf(z1, s_sv[16 + k], s_mean[16 + k]);  // batch b+256 sample
        }
        // stable softmax over k, both batches
        float m0 = x0v[0], m1 = x1v[0];
#pragma unroll
        for (int k = 1; k < 16; k++) { m0 = fmaxf(m0, x0v[k]); m1 = fmaxf(m1, x1v[k]); }
        float sum0 = 0.f, sum1 = 0.f;
#pragma unroll
        for (int k = 0; k < 16; k++) {
            x0v[k] = __expf(x0v[k] - m0); sum0 += x0v[k];
            x1v[k] = __expf(x1v[k] - m1); sum1 += x1v[k];
        }
        float inv0 = 1.0f / sum0, inv1 = 1.0f / sum1;
#pragma unroll
        for (int k = 0; k < 16; k++) {
            float p0 = x0v[k] * inv0;
            float p1 = x1v[k] * inv1;
            accs0[k] += p0; accq0[k] = fmaf(p0, p0, accq0[k]);
            accs1[k] += p1; accq1[k] = fmaf(p1, p1, accq1[k]);
        }
    }

    // reduce 64 accumulators across the block: wave shuffle -> LDS -> wave 0
    const int lane = tid & 63, wave = tid >> 6;
#pragma unroll
    for (int k = 0; k < 16; k++) {
        float v0 = wave_sum(accs0[k]);
        float q0 = wave_sum(accq0[k]);
        float v1 = wave_sum(accs1[k]);
        float q1 = wave_sum(accq1[k]);
        if (lane == 0) {
            s_red[wave * 64 + k * 4 + 0] = v0;
            s_red[wave * 64 + k * 4 + 1] = q0;
            s_red[wave * 64 + k * 4 + 2] = v1;
            s_red[wave * 64 + k * 4 + 3] = q1;
        }
    }
    __syncthreads();

    if (tid < 32) {
        int h = tid >> 4, k = tid & 15;
        float sum = 0.f, sq = 0.f;
#pragma unroll
        for (int w = 0; w < 8; w++) {
            sum += s_red[w * 64 + k * 4 + 2 * h + 0];
            sq  += s_red[w * 64 + k * 4 + 2 * h + 1];
        }
        const float invN = 1.0f / 10000.0f;
        float mu = sum * invN;
        float vr = (sq - sum * mu) * (1.0f / 9999.0f);  // unbiased
        int bg = b + 256 * h;
        out[bg * 16 + k] = mu;
        out[8192 + bg * 16 + k] = vr;
    }
}

extern "C" void kernel_launch(void* const* d_in, const int* in_sizes, int n_in,
                              void* d_out, int out_size, void* d_ws, size_t ws_size,
                              hipStream_t stream) {
    const float* mean = (const float*)d_in[0];
    const float* var  = (const float*)d_in[1];
    float* out = (float*)d_out;
    sg_kernel<<<256, THREADS, 0, stream>>>(mean, var, out);
}

// Round 2
// 184.619 us; speedup vs baseline: 1.0495x; 1.0495x over previous
//
#include <hip/hip_runtime.h>
#include <cstdint>
#include <math.h>

// SoftmaxGaussian: out_mean/out_var over 10000 MC softmax samples with
// JAX threefry2x32-exact random draw (key(42), shape (512,16,10000)).
//
// Layout facts:
//   N = 512*16*10000 = 81,920,000 ; half = 40,960,000 = 256*16*10000
//   flat j=(b*16+k)*10000+s ; threefry block i in [0,half):
//     counters (i, i+half), key (0,42) -> (z[j=i], z[j=i+half])
//   => block i yields samples for (b,k,s) AND (b+256,k,s). One b per block-row.
//
// R2: 4-way sample split (1024 blocks -> occupancy 23%->~46%) + branchless
// XLA/Giles erfinv polynomial (the exact algorithm XLA lowers erf_inv to,
// so it tracks the JAX reference better than ocml erfinvf AND is cheaper).

#define NSAMP 10000
#define HALF_N 40960000u
#define THREADS 512
#define SPLIT 4
#define CHUNK (NSAMP / SPLIT)  // 2500
#define WS_NEEDED (256 * SPLIT * 64 * sizeof(float))  // 262144 B

__device__ __forceinline__ uint32_t rotl32(uint32_t x, int r) {
    return (x << r) | (x >> (32 - r));  // v_alignbit_b32
}

// JAX threefry2x32, key = (0, 42)
__device__ __forceinline__ void threefry2x32_k42(uint32_t x0, uint32_t x1,
                                                 uint32_t& o0, uint32_t& o1) {
    const uint32_t ks0 = 0u;
    const uint32_t ks1 = 42u;
    const uint32_t ks2 = 0x1BD11BDAu ^ 0u ^ 42u;
    x0 += ks0;
    x1 += ks1;
#define TF_R(r) { x0 += x1; x1 = rotl32(x1, r); x1 ^= x0; }
    TF_R(13) TF_R(15) TF_R(26) TF_R(6)   x0 += ks1; x1 += ks2 + 1u;
    TF_R(17) TF_R(29) TF_R(16) TF_R(24)  x0 += ks2; x1 += ks0 + 2u;
    TF_R(13) TF_R(15) TF_R(26) TF_R(6)   x0 += ks0; x1 += ks1 + 3u;
    TF_R(17) TF_R(29) TF_R(16) TF_R(24)  x0 += ks1; x1 += ks2 + 4u;
    TF_R(13) TF_R(15) TF_R(26) TF_R(6)   x0 += ks2; x1 += ks0 + 5u;
#undef TF_R
    o0 = x0;
    o1 = x1;
}

// JAX uniform(lo=nextafter(-1,0), hi=1) from raw bits (float32 path)
__device__ __forceinline__ float u_from_bits(uint32_t bits) {
    float f = __uint_as_float((bits >> 9) | 0x3F800000u) - 1.0f; // [0,1)
    const float lo = -0.99999994f;                               // nextafterf(-1,0)
    return fmaxf(lo, fmaf(f, 1.0f - lo, lo));
}

// XLA's ErfInv f32 (Giles 2012) — branchless both-path eval + select.
// |x| <= 1-2^-24 here, so w = -log(1-x^2) <= ~16.6 and both paths are finite.
__device__ __forceinline__ float erfinv_giles(float x) {
    float w = -__logf(fmaf(-x, x, 1.0f));
    // main path (w < 5)
    float wm = w - 2.5f;
    float p1 = 2.81022636e-08f;
    p1 = fmaf(p1, wm, 3.43273939e-07f);
    p1 = fmaf(p1, wm, -3.5233877e-06f);
    p1 = fmaf(p1, wm, -4.39150654e-06f);
    p1 = fmaf(p1, wm, 0.00021858087f);
    p1 = fmaf(p1, wm, -0.00125372503f);
    p1 = fmaf(p1, wm, -0.00417768164f);
    p1 = fmaf(p1, wm, 0.246640727f);
    p1 = fmaf(p1, wm, 1.50140941f);
    // tail path (w >= 5)
    float wt = sqrtf(w) - 3.0f;
    float p2 = -0.000200214257f;
    p2 = fmaf(p2, wt, 0.000100950558f);
    p2 = fmaf(p2, wt, 0.00134934322f);
    p2 = fmaf(p2, wt, -0.00367342844f);
    p2 = fmaf(p2, wt, 0.00573950773f);
    p2 = fmaf(p2, wt, -0.0076224613f);
    p2 = fmaf(p2, wt, 0.00943887047f);
    p2 = fmaf(p2, wt, 1.00167406f);
    p2 = fmaf(p2, wt, 2.83297682f);
    float p = (w < 5.0f) ? p1 : p2;
    return p * x;
}

__device__ __forceinline__ float wave_sum(float v) {
    v += __shfl_down(v, 32);
    v += __shfl_down(v, 16);
    v += __shfl_down(v, 8);
    v += __shfl_down(v, 4);
    v += __shfl_down(v, 2);
    v += __shfl_down(v, 1);
    return v;
}

// Accumulate samples [s_begin, s_end) for batch-row b (and b+256) and leave
// the block-reduced 64 partials {sum0,sq0,sum1,sq1} per k in s_fin[64].
__device__ __forceinline__ void sg_accumulate(const float* __restrict__ mean,
                                              const float* __restrict__ var,
                                              int b, int s_begin, int s_end,
                                              float* s_mean, float* s_sv,
                                              float* s_red, float* s_fin) {
    const int tid = threadIdx.x;

    if (tid < 32) {
        int h = tid >> 4, k = tid & 15;
        int bg = b + 256 * h;
        s_mean[tid] = mean[bg * 16 + k];
        s_sv[tid] = 1.41421356237309515f * sqrtf(var[bg * 16 + k]);
    }
    __syncthreads();

    float accs0[16], accq0[16], accs1[16], accq1[16];
#pragma unroll
    for (int k = 0; k < 16; k++) { accs0[k] = 0.f; accq0[k] = 0.f; accs1[k] = 0.f; accq1[k] = 0.f; }

    const uint32_t base_bk = (uint32_t)(b * 16) * 10000u;

    for (int s = s_begin + tid; s < s_end; s += THREADS) {
        float x0v[16], x1v[16];
#pragma unroll
        for (int k = 0; k < 16; k++) {
            uint32_t i = base_bk + (uint32_t)(k * 10000) + (uint32_t)s;
            uint32_t o0, o1;
            threefry2x32_k42(i, i + HALF_N, o0, o1);
            float z0 = erfinv_giles(u_from_bits(o0));
            float z1 = erfinv_giles(u_from_bits(o1));
            x0v[k] = fmaf(z0, s_sv[k],      s_mean[k]);       // batch b
            x1v[k] = fmaf(z1, s_sv[16 + k], s_mean[16 + k]);  // batch b+256
        }
        float m0 = x0v[0], m1 = x1v[0];
#pragma unroll
        for (int k = 1; k < 16; k++) { m0 = fmaxf(m0, x0v[k]); m1 = fmaxf(m1, x1v[k]); }
        float sum0 = 0.f, sum1 = 0.f;
#pragma unroll
        for (int k = 0; k < 16; k++) {
            x0v[k] = __expf(x0v[k] - m0); sum0 += x0v[k];
            x1v[k] = __expf(x1v[k] - m1); sum1 += x1v[k];
        }
        float inv0 = 1.0f / sum0, inv1 = 1.0f / sum1;
#pragma unroll
        for (int k = 0; k < 16; k++) {
            float p0 = x0v[k] * inv0;
            float p1 = x1v[k] * inv1;
            accs0[k] += p0; accq0[k] = fmaf(p0, p0, accq0[k]);
            accs1[k] += p1; accq1[k] = fmaf(p1, p1, accq1[k]);
        }
    }

    const int lane = tid & 63, wave = tid >> 6;
#pragma unroll
    for (int k = 0; k < 16; k++) {
        float v0 = wave_sum(accs0[k]);
        float q0 = wave_sum(accq0[k]);
        float v1 = wave_sum(accs1[k]);
        float q1 = wave_sum(accq1[k]);
        if (lane == 0) {
            s_red[wave * 64 + k * 4 + 0] = v0;
            s_red[wave * 64 + k * 4 + 1] = q0;
            s_red[wave * 64 + k * 4 + 2] = v1;
            s_red[wave * 64 + k * 4 + 3] = q1;
        }
    }
    __syncthreads();

    if (tid < 64) {
        float t = 0.f;
#pragma unroll
        for (int w = 0; w < 8; w++) t += s_red[w * 64 + tid];
        s_fin[tid] = t;
    }
    __syncthreads();
}

// ---- split path: 256*SPLIT blocks write partials to ws ----
__global__ __launch_bounds__(THREADS, 4)
void sg_partial(const float* __restrict__ mean, const float* __restrict__ var,
                float* __restrict__ ws) {
    __shared__ float s_mean[32], s_sv[32], s_red[8 * 64], s_fin[64];
    const int b = blockIdx.x >> 2;       // 0..255
    const int chunk = blockIdx.x & 3;    // 0..SPLIT-1
    sg_accumulate(mean, var, b, chunk * CHUNK, (chunk + 1) * CHUNK,
                  s_mean, s_sv, s_red, s_fin);
    if (threadIdx.x < 64) ws[blockIdx.x * 64 + threadIdx.x] = s_fin[threadIdx.x];
}

__global__ __launch_bounds__(256)
void sg_finalize(const float* __restrict__ ws, float* __restrict__ out) {
    int t = blockIdx.x * blockDim.x + threadIdx.x;  // 0..8191
    if (t >= 8192) return;
    int k = t & 15, h = (t >> 4) & 1, b = t >> 5;
    float sum = 0.f, sq = 0.f;
#pragma unroll
    for (int c = 0; c < SPLIT; c++) {
        const float* p = ws + ((b * SPLIT + c) * 64 + k * 4 + 2 * h);
        sum += p[0];
        sq += p[1];
    }
    float mu = sum * (1.0f / 10000.0f);
    float vr = (sq - sum * mu) * (1.0f / 9999.0f);  // unbiased
    int bg = b + 256 * h;
    out[bg * 16 + k] = mu;
    out[8192 + bg * 16 + k] = vr;
}

// ---- fallback (ws too small): single kernel, one block per b ----
__global__ __launch_bounds__(THREADS, 2)
void sg_kernel(const float* __restrict__ mean, const float* __restrict__ var,
               float* __restrict__ out) {
    __shared__ float s_mean[32], s_sv[32], s_red[8 * 64], s_fin[64];
    const int b = blockIdx.x;
    sg_accumulate(mean, var, b, 0, NSAMP, s_mean, s_sv, s_red, s_fin);
    const int tid = threadIdx.x;
    if (tid < 32) {
        int h = tid >> 4, k = tid & 15;
        float sum = s_fin[k * 4 + 2 * h + 0];
        float sq  = s_fin[k * 4 + 2 * h + 1];
        float mu = sum * (1.0f / 10000.0f);
        float vr = (sq - sum * mu) * (1.0f / 9999.0f);
        int bg = b + 256 * h;
        out[bg * 16 + k] = mu;
        out[8192 + bg * 16 + k] = vr;
    }
}

extern "C" void kernel_launch(void* const* d_in, const int* in_sizes, int n_in,
                              void* d_out, int out_size, void* d_ws, size_t ws_size,
                              hipStream_t stream) {
    const float* mean = (const float*)d_in[0];
    const float* var  = (const float*)d_in[1];
    float* out = (float*)d_out;
    if (ws_size >= WS_NEEDED) {
        float* ws = (float*)d_ws;
        sg_partial<<<256 * SPLIT, THREADS, 0, stream>>>(mean, var, ws);
        sg_finalize<<<32, 256, 0, stream>>>(ws, out);
    } else {
        sg_kernel<<<256, THREADS, 0, stream>>>(mean, var, out);
    }
}